// Round 6
// baseline (733.637 us; speedup 1.0000x reference)
//
#include <hip/hip_runtime.h>
#include <math.h>

typedef unsigned short u16;
typedef unsigned int   u32;
typedef __attribute__((ext_vector_type(8))) short short8;
typedef __attribute__((ext_vector_type(4))) float f32x4;

#define NPTS 4096
#define NB   16
#define FLT_BIG 3.402823466e38f

// ---- workspace layout (float offsets), total ~221 MB ----
static const size_t OFF_Y1  = 0;          // 16,777,216 f
static const size_t OFF_Y2  = 16777216;   // 33,554,432 f
static const size_t OFF_W1I = 50331648;   // 344064 u16 -> 172032 f
static const size_t OFF_W2I = 50503680;   // 262144 u16 -> 131072 f
static const size_t OFF_W3I = 50634752;   // 1048576 u16 -> 524288 f
static const size_t OFF_PS  = 51159040;   // 1,048,576
static const size_t OFF_PQ  = 52207616;   // 1,048,576
static const size_t OFF_PMX = 53256192;   // 1,048,576
static const size_t OFF_PMN = 54304768;   // 1,048,576
static const size_t OFF_ASH = 55353344;   // 2048 (float2[1024])

__device__ __forceinline__ void gload_lds16(const void* g, void* l) {
    __builtin_amdgcn_global_load_lds(
        (const __attribute__((address_space(1))) u32*)g,
        (__attribute__((address_space(3))) u32*)l, 16, 0, 0);
}
__device__ __forceinline__ u32 pk(u32 a, u32 b) {   // [b.hi16 | a.hi16] -> u16 pair (a first)
    return __builtin_amdgcn_perm(b, a, 0x07060302u);
}

// ---- W prep: 2-plane (hi,mid) image in GEMM-ready order ----
// per (chunk,kt) tile of 16384 u16: [plane 2][kot 4][m 256][8k]
__global__ __launch_bounds__(256) void prep_w(const float* __restrict__ W1,
                                              const float* __restrict__ W2,
                                              const float* __restrict__ W3,
                                              u16* __restrict__ w1i,
                                              u16* __restrict__ w2i,
                                              u16* __restrict__ w3i) {
    const int bx = blockIdx.x;
    const float* W; u16* img; int Kact, KT, mc, kt;
    if (bx < 21)      { W = W1; img = w1i; Kact = 643; KT = 21; mc = 0;              kt = bx; }
    else if (bx < 37) { W = W2; img = w2i; Kact = 256; KT = 8;  mc = (bx - 21) >> 3; kt = (bx - 21) & 7; }
    else              { W = W3; img = w3i; Kact = 512; KT = 16; mc = (bx - 37) >> 4; kt = (bx - 37) & 15; }

    u16* tb = img + ((size_t)(mc * KT + kt) << 14);
    for (int it = 0; it < 4; ++it) {
        const int item = it * 256 + threadIdx.x;
        const int m = item & 255, kot = item >> 8;
        const int k0 = kt * 32 + kot * 8;
        const float* wr = W + (size_t)(mc * 256 + m) * Kact;
        u32 hh[8], mm[8];
#pragma unroll
        for (int j = 0; j < 8; ++j) {
            const int k = k0 + j;
            const float x = (k < Kact) ? wr[k] : 0.f;
            const u32 u = __float_as_uint(x);
            const u32 uh = u + 0x8000u;
            const float r1 = x - __uint_as_float(uh & 0xFFFF0000u);
            hh[j] = uh;
            mm[j] = __float_as_uint(r1) + 0x8000u;
        }
        uint4 wh, wmv;
        wh.x = pk(hh[0], hh[1]); wh.y = pk(hh[2], hh[3]);
        wh.z = pk(hh[4], hh[5]); wh.w = pk(hh[6], hh[7]);
        wmv.x = pk(mm[0], mm[1]); wmv.y = pk(mm[2], mm[3]);
        wmv.z = pk(mm[4], mm[5]); wmv.w = pk(mm[6], mm[7]);
        u16* dst = tb + kot * 2048 + m * 8;
        *(uint4*)dst          = wh;    // plane 0 (hi)
        *(uint4*)(dst + 8192) = wmv;   // plane 1 (mid)
    }
}

// ---- fused 3-product split-bf16 MFMA GEMM ----
// block: 512 threads (8 waves, 4m x 2n), M-chunk = 256, N-tile = 128, K-step 32,
// SINGLE-buffered LDS (48KB -> 3 blocks/CU) with register B-prefetch overlapping compute.
template<bool BN_IN, bool STORE, bool MAXMIN>
__global__ __launch_bounds__(512, 4)
void gemm3p(const u16* __restrict__ Wimg, int KT, int Kact, int M_,
            const float* __restrict__ bias,
            const float* __restrict__ X,            // [NB][Kact][4096] fp32
            const float2* __restrict__ ash,
            float* __restrict__ Y,
            float* __restrict__ psum, float* __restrict__ psq,
            float* __restrict__ pmax, float* __restrict__ pmin)
{
    __shared__ __align__(16) u16 As_[16384];   // [plane 2][kot 4][m 256][8k]
    __shared__ __align__(16) u16 Bs_[8192];    // [plane 2][kot 4][n 128][8k]

    const int tid = threadIdx.x;
    const int lane = tid & 63, wid = tid >> 6;
    const int l15 = lane & 15, l4 = lane >> 4;
    const int wm = wid >> 1, wn = wid & 1;
    const int nt = blockIdx.x, mtb = blockIdx.y, b = blockIdx.z;
    const int m0 = mtb * 256, n0 = nt * 128;
    const int nb = tid & 127, kob = tid >> 7;

    f32x4 acc[4][4];
#pragma unroll
    for (int i = 0; i < 4; ++i)
#pragma unroll
        for (int j = 0; j < 4; ++j) acc[i][j] = (f32x4){0.f, 0.f, 0.f, 0.f};

    const u16* wtile = Wimg + ((size_t)mtb * KT << 14);

    // invariant offsets (u16 units)
    const int afo = l4 * 2048 + (wm * 64 + l15) * 8;   // + mf*128, + plane*8192
    const int bfo = l4 * 1024 + (wn * 64 + l15) * 8;   // + nf*128, + plane*4096
    const int bwo = kob * 1024 + nb * 8;               // staging write

    float xr[8]; float2 ar[8];

#define STAGE_A(kt)                                                               \
    {                                                                             \
        const u16* g_ = wtile + ((size_t)(kt) << 14);                             \
        _Pragma("unroll")                                                         \
        for (int i_ = 0; i_ < 4; ++i_)                                            \
            gload_lds16(g_ + wid * 2048 + i_ * 512 + lane * 8,                    \
                        As_ + wid * 2048 + i_ * 512);                             \
    }

#define READ_B(kt)                                                                \
    {                                                                             \
        const int kb_ = (kt) * 32 + kob * 8;                                      \
        const float* src_ = X + ((size_t)b * Kact + kb_) * NPTS + n0 + nb;        \
        _Pragma("unroll")                                                         \
        for (int j_ = 0; j_ < 8; ++j_) {                                          \
            const int k_ = kb_ + j_;                                              \
            xr[j_] = (k_ < Kact) ? src_[(size_t)j_ * NPTS] : 0.f;                 \
            if (BN_IN) ar[j_] = ash[(k_ < Kact) ? k_ : 0];                        \
        }                                                                         \
    }

#define WRITE_B()                                                                 \
    {                                                                             \
        u32 hh_[8], mm_[8];                                                       \
        _Pragma("unroll")                                                         \
        for (int j_ = 0; j_ < 8; ++j_) {                                          \
            float x_ = xr[j_];                                                    \
            if (BN_IN) x_ = fmaxf(fmaf(ar[j_].x, x_, ar[j_].y), 0.f);             \
            const u32 u_ = __float_as_uint(x_);                                   \
            const u32 uh_ = u_ + 0x8000u;                                         \
            const float r1_ = x_ - __uint_as_float(uh_ & 0xFFFF0000u);            \
            hh_[j_] = uh_;                                                        \
            mm_[j_] = __float_as_uint(r1_) + 0x8000u;                             \
        }                                                                         \
        uint4 wh_, wm_;                                                           \
        wh_.x = pk(hh_[0], hh_[1]); wh_.y = pk(hh_[2], hh_[3]);                   \
        wh_.z = pk(hh_[4], hh_[5]); wh_.w = pk(hh_[6], hh_[7]);                   \
        wm_.x = pk(mm_[0], mm_[1]); wm_.y = pk(mm_[2], mm_[3]);                   \
        wm_.z = pk(mm_[4], mm_[5]); wm_.w = pk(mm_[6], mm_[7]);                   \
        *(uint4*)(Bs_ + bwo)        = wh_;                                        \
        *(uint4*)(Bs_ + 4096 + bwo) = wm_;                                        \
    }

#define COMPUTE()                                                                 \
    {                                                                             \
        short8 ah_[4], am_[4];                                                    \
        _Pragma("unroll")                                                         \
        for (int mf_ = 0; mf_ < 4; ++mf_) {                                       \
            ah_[mf_] = *(const short8*)(As_ + afo + mf_ * 128);                   \
            am_[mf_] = *(const short8*)(As_ + 8192 + afo + mf_ * 128);            \
        }                                                                         \
        _Pragma("unroll")                                                         \
        for (int nf_ = 0; nf_ < 4; ++nf_) {                                       \
            const short8 bh_ = *(const short8*)(Bs_ + bfo + nf_ * 128);           \
            const short8 bm_ = *(const short8*)(Bs_ + 4096 + bfo + nf_ * 128);    \
            _Pragma("unroll")                                                     \
            for (int mf_ = 0; mf_ < 4; ++mf_)                                     \
                acc[mf_][nf_] = __builtin_amdgcn_mfma_f32_16x16x32_bf16(          \
                    ah_[mf_], bh_, acc[mf_][nf_], 0, 0, 0);                       \
            _Pragma("unroll")                                                     \
            for (int mf_ = 0; mf_ < 4; ++mf_)                                     \
                acc[mf_][nf_] = __builtin_amdgcn_mfma_f32_16x16x32_bf16(          \
                    ah_[mf_], bm_, acc[mf_][nf_], 0, 0, 0);                       \
            _Pragma("unroll")                                                     \
            for (int mf_ = 0; mf_ < 4; ++mf_)                                     \
                acc[mf_][nf_] = __builtin_amdgcn_mfma_f32_16x16x32_bf16(          \
                    am_[mf_], bh_, acc[mf_][nf_], 0, 0, 0);                       \
        }                                                                         \
    }

    READ_B(0);
    for (int kt = 0; kt < KT; ++kt) {
        __syncthreads();               // previous compute done; LDS reusable
        STAGE_A(kt);                   // async global->LDS (A)
        WRITE_B();                     // regs -> LDS (B), BN+ReLU+split
        __syncthreads();               // staging visible
        if (kt + 1 < KT) READ_B(kt + 1);   // prefetch next B during compute
        COMPUTE();
    }

    // ---- epilogue: bias, stats partials, optional store / max-min partials ----
#pragma unroll
    for (int mf = 0; mf < 4; ++mf) {
#pragma unroll
        for (int r = 0; r < 4; ++r) {
            const int m = m0 + wm * 64 + mf * 16 + l4 * 4 + r;
            const float bvv = bias[m];
            float vs[4];
            float rs = 0.f, rq = 0.f;
#pragma unroll
            for (int nf = 0; nf < 4; ++nf) {
                const float v = acc[mf][nf][r] + bvv;
                vs[nf] = v; rs += v; rq = fmaf(v, v, rq);
            }
            float mx = 0.f, mn = 0.f;
            if (MAXMIN) {
                mx = fmaxf(fmaxf(vs[0], vs[1]), fmaxf(vs[2], vs[3]));
                mn = fminf(fminf(vs[0], vs[1]), fminf(vs[2], vs[3]));
            }
            if (STORE) {
#pragma unroll
                for (int nf = 0; nf < 4; ++nf)
                    Y[((size_t)b * M_ + m) * NPTS + n0 + wn * 64 + nf * 16 + l15] = vs[nf];
            }
#pragma unroll
            for (int s = 1; s < 16; s <<= 1) {
                rs += __shfl_xor(rs, s);
                rq += __shfl_xor(rq, s);
                if (MAXMIN) {
                    mx = fmaxf(mx, __shfl_xor(mx, s));
                    mn = fminf(mn, __shfl_xor(mn, s));
                }
            }
            if (l15 == 0) {
                const int slot = (b * 32 + nt) * 2 + wn;
                psum[(size_t)slot * M_ + m] = rs;
                psq[(size_t)slot * M_ + m]  = rq;
                if (MAXMIN) {
                    pmax[((size_t)b * M_ + m) * 64 + nt * 2 + wn] = mx;
                    pmin[((size_t)b * M_ + m) * 64 + nt * 2 + wn] = mn;
                }
            }
        }
    }
#undef STAGE_A
#undef READ_B
#undef WRITE_B
#undef COMPUTE
}

// ---- per-channel stats (1024 slots) -> BN scale/shift (packed float2) ----
__global__ __launch_bounds__(256) void stats_k(const float* __restrict__ psum, const float* __restrict__ psq,
                                               int M_,
                                               const float* __restrict__ g, const float* __restrict__ be,
                                               float2* __restrict__ ash)
{
    __shared__ double ds[4][64];
    __shared__ double dq[4][64];
    const int mloc = threadIdx.x & 63, q = threadIdx.x >> 6;
    const int m = blockIdx.x * 64 + mloc;
    double s = 0.0, sq = 0.0;
    for (int sl = q * 256; sl < (q + 1) * 256; ++sl) {
        s  += (double)psum[(size_t)sl * M_ + m];
        sq += (double)psq[(size_t)sl * M_ + m];
    }
    ds[q][mloc] = s; dq[q][mloc] = sq;
    __syncthreads();
    if (threadIdx.x < 64) {
        const double S = ds[0][mloc] + ds[1][mloc] + ds[2][mloc] + ds[3][mloc];
        const double Q = dq[0][mloc] + dq[1][mloc] + dq[2][mloc] + dq[3][mloc];
        const double cnt = (double)NB * (double)NPTS;
        double mean = S / cnt;
        double var  = Q / cnt - mean * mean;
        if (var < 0.0) var = 0.0;
        const double a = (double)g[m] / sqrt(var + 1e-5);
        ash[m] = make_float2((float)a, (float)((double)be[m] - a * mean));
    }
}

// ---- final: fused L3-stats, pool-select, BN-apply+ReLU, BN1d over batch ----
__global__ __launch_bounds__(256) void final_k(const float* __restrict__ psum, const float* __restrict__ psq,
                                               const float* __restrict__ g3, const float* __restrict__ be3,
                                               const float* __restrict__ pmax, const float* __restrict__ pmin,
                                               const float* __restrict__ g4, const float* __restrict__ be4,
                                               float* __restrict__ out)
{
    const int c = blockIdx.x * 256 + threadIdx.x;
    if (c >= 1024) return;
    double S = 0.0, Q = 0.0;
    for (int sl = 0; sl < 1024; ++sl) {
        S += (double)psum[(size_t)sl * 1024 + c];
        Q += (double)psq[(size_t)sl * 1024 + c];
    }
    const double cnt = (double)NB * (double)NPTS;
    double mean3 = S / cnt;
    double var3  = Q / cnt - mean3 * mean3;
    if (var3 < 0.0) var3 = 0.0;
    const double a3 = (double)g3[c] / sqrt(var3 + 1e-5);
    const float a = (float)a3;
    const float sh = (float)((double)be3[c] - a3 * mean3);

    float h[NB];
    float s = 0.f;
    for (int b = 0; b < NB; ++b) {
        float mxv = -FLT_BIG, mnv = FLT_BIG;
        const float* pxr = pmax + ((size_t)b * 1024 + c) * 64;
        const float* pnr = pmin + ((size_t)b * 1024 + c) * 64;
        for (int q = 0; q < 64; ++q) {
            mxv = fmaxf(mxv, pxr[q]);
            mnv = fminf(mnv, pnr[q]);
        }
        const float v = (a >= 0.f) ? fmaf(a, mxv, sh) : fmaf(a, mnv, sh);
        h[b] = fmaxf(v, 0.f);
        s += h[b];
    }
    const float mean = s * (1.f / NB);
    float var = 0.f;
    for (int b = 0; b < NB; ++b) { const float d = h[b] - mean; var = fmaf(d, d, var); }
    var *= (1.f / NB);
    const double ai = (double)g4[c] / sqrt((double)var + 1e-5);
    for (int b = 0; b < NB; ++b)
        out[b * 1024 + c] = (float)(ai * ((double)h[b] - (double)mean) + (double)be4[c]);
}

extern "C" void kernel_launch(void* const* d_in, const int* in_sizes, int n_in,
                              void* d_out, int out_size, void* d_ws, size_t ws_size,
                              hipStream_t stream) {
    const float* xyz = (const float*)d_in[0];
    const float* W1  = (const float*)d_in[1];
    const float* b1  = (const float*)d_in[2];
    const float* g1  = (const float*)d_in[3];
    const float* be1 = (const float*)d_in[4];
    const float* W2  = (const float*)d_in[5];
    const float* b2  = (const float*)d_in[6];
    const float* g2  = (const float*)d_in[7];
    const float* be2 = (const float*)d_in[8];
    const float* W3  = (const float*)d_in[9];
    const float* b3  = (const float*)d_in[10];
    const float* g3  = (const float*)d_in[11];
    const float* be3 = (const float*)d_in[12];
    const float* g4  = (const float*)d_in[13];
    const float* be4 = (const float*)d_in[14];

    float* ws = (float*)d_ws;
    float* y1  = ws + OFF_Y1;
    float* y2  = ws + OFF_Y2;
    u16*   w1i = (u16*)(ws + OFF_W1I);
    u16*   w2i = (u16*)(ws + OFF_W2I);
    u16*   w3i = (u16*)(ws + OFF_W3I);
    float* ps  = ws + OFF_PS;
    float* pq  = ws + OFF_PQ;
    float* pmx = ws + OFF_PMX;
    float* pmn = ws + OFF_PMN;
    float2* ash = (float2*)(ws + OFF_ASH);
    float* out = (float*)d_out;

    // W images: L1 21 tiles, L2 16, L3 64
    prep_w<<<101, 256, 0, stream>>>(W1, W2, W3, w1i, w2i, w3i);

    // L1: y1 = W1 @ xyz + b1 (store + stats). grid (nt=32, mtb=1, b=16)
    gemm3p<false, true, false><<<dim3(32, 1, 16), 512, 0, stream>>>(
        w1i, 21, 643, 256, b1, xyz, nullptr,
        y1, ps, pq, nullptr, nullptr);
    stats_k<<<4, 256, 0, stream>>>(ps, pq, 256, g1, be1, ash);

    // L2: y2 = W2 @ relu(bn(y1)) + b2 (store + stats). grid (32, 2, 16)
    gemm3p<true, true, false><<<dim3(32, 2, 16), 512, 0, stream>>>(
        w2i, 8, 256, 512, b2, y1, ash,
        y2, ps, pq, nullptr, nullptr);
    stats_k<<<8, 256, 0, stream>>>(ps, pq, 512, g2, be2, ash);

    // L3: stats + per-(b,m) max/min partials (no store). grid (32, 4, 16)
    gemm3p<true, false, true><<<dim3(32, 4, 16), 512, 0, stream>>>(
        w3i, 16, 512, 1024, b3, y2, ash,
        nullptr, ps, pq, pmx, pmn);

    // fused L3-stats + pool-select + final BN1d
    final_k<<<4, 256, 0, stream>>>(ps, pq, g3, be3, pmx, pmn, g4, be4, out);
}

// Round 7
// 704.188 us; speedup vs baseline: 1.0418x; 1.0418x over previous
//
#include <hip/hip_runtime.h>
#include <math.h>

typedef unsigned short u16;
typedef unsigned int   u32;
typedef __attribute__((ext_vector_type(8))) short short8;
typedef __attribute__((ext_vector_type(4))) float f32x4;

#define NPTS 4096
#define NB   16
#define FLT_BIG 3.402823466e38f

// ---- workspace layout (float offsets), total ~221 MB ----
static const size_t OFF_Y1  = 0;          // 16,777,216 f
static const size_t OFF_Y2  = 16777216;   // 33,554,432 f
static const size_t OFF_W1I = 50331648;   // 344064 u16 -> 172032 f
static const size_t OFF_W2I = 50503680;   // 262144 u16 -> 131072 f
static const size_t OFF_W3I = 50634752;   // 1048576 u16 -> 524288 f
static const size_t OFF_PS  = 51159040;   // 1,048,576
static const size_t OFF_PQ  = 52207616;   // 1,048,576
static const size_t OFF_PMX = 53256192;   // 1,048,576
static const size_t OFF_PMN = 54304768;   // 1,048,576
static const size_t OFF_ASH = 55353344;   // 2048 (float2[1024])

__device__ __forceinline__ void gload_lds16(const void* g, void* l) {
    __builtin_amdgcn_global_load_lds(
        (const __attribute__((address_space(1))) u32*)g,
        (__attribute__((address_space(3))) u32*)l, 16, 0, 0);
}
__device__ __forceinline__ u32 pk(u32 a, u32 b) {   // [b.hi16 | a.hi16] -> u16 pair (a first)
    return __builtin_amdgcn_perm(b, a, 0x07060302u);
}

// ---- W prep: 2-plane (hi,mid) image in GEMM-ready order ----
// per (chunk,kt) tile of 16384 u16: [plane 2][kot 4][m 256][8k]
__global__ __launch_bounds__(256) void prep_w(const float* __restrict__ W1,
                                              const float* __restrict__ W2,
                                              const float* __restrict__ W3,
                                              u16* __restrict__ w1i,
                                              u16* __restrict__ w2i,
                                              u16* __restrict__ w3i) {
    const int bx = blockIdx.x;
    const float* W; u16* img; int Kact, KT, mc, kt;
    if (bx < 21)      { W = W1; img = w1i; Kact = 643; KT = 21; mc = 0;              kt = bx; }
    else if (bx < 37) { W = W2; img = w2i; Kact = 256; KT = 8;  mc = (bx - 21) >> 3; kt = (bx - 21) & 7; }
    else              { W = W3; img = w3i; Kact = 512; KT = 16; mc = (bx - 37) >> 4; kt = (bx - 37) & 15; }

    u16* tb = img + ((size_t)(mc * KT + kt) << 14);
    for (int it = 0; it < 4; ++it) {
        const int item = it * 256 + threadIdx.x;
        const int m = item & 255, kot = item >> 8;
        const int k0 = kt * 32 + kot * 8;
        const float* wr = W + (size_t)(mc * 256 + m) * Kact;
        u32 hh[8], mm[8];
#pragma unroll
        for (int j = 0; j < 8; ++j) {
            const int k = k0 + j;
            const float x = (k < Kact) ? wr[k] : 0.f;
            const u32 u = __float_as_uint(x);
            const u32 uh = u + 0x8000u;
            const float r1 = x - __uint_as_float(uh & 0xFFFF0000u);
            hh[j] = uh;
            mm[j] = __float_as_uint(r1) + 0x8000u;
        }
        uint4 wh, wmv;
        wh.x = pk(hh[0], hh[1]); wh.y = pk(hh[2], hh[3]);
        wh.z = pk(hh[4], hh[5]); wh.w = pk(hh[6], hh[7]);
        wmv.x = pk(mm[0], mm[1]); wmv.y = pk(mm[2], mm[3]);
        wmv.z = pk(mm[4], mm[5]); wmv.w = pk(mm[6], mm[7]);
        u16* dst = tb + kot * 2048 + m * 8;
        *(uint4*)dst          = wh;    // plane 0 (hi)
        *(uint4*)(dst + 8192) = wmv;   // plane 1 (mid)
    }
}

// ---- fused 3-product split-bf16 MFMA GEMM ----
// block: 512 threads (8 waves, 4m x 2n), M-chunk 256, N-tile 128, K-step 32.
// A double-buffered LDS (prefetch issued AFTER publish barrier -> flies under compute);
// B register-prefetched. LDS = 80KB -> 2 blocks/CU.
template<bool BN_IN, bool STORE, bool MAXMIN>
__global__ __launch_bounds__(512, 2)
void gemm3p(const u16* __restrict__ Wimg, int KT, int Kact, int M_,
            const float* __restrict__ bias,
            const float* __restrict__ X,            // [NB][Kact][4096] fp32
            const float2* __restrict__ ash,
            float* __restrict__ Y,
            float* __restrict__ psum, float* __restrict__ psq,
            float* __restrict__ pmax, float* __restrict__ pmin)
{
    __shared__ __align__(16) u16 As_[2 * 16384];   // [buf][plane 2][kot 4][m 256][8k]
    __shared__ __align__(16) u16 Bs_[8192];        // [plane 2][kot 4][n 128][8k]

    const int tid = threadIdx.x;
    const int lane = tid & 63, wid = tid >> 6;
    const int l15 = lane & 15, l4 = lane >> 4;
    const int wm = wid >> 1, wn = wid & 1;
    const int nt = blockIdx.x, mtb = blockIdx.y, b = blockIdx.z;
    const int m0 = mtb * 256, n0 = nt * 128;
    const int nb = tid & 127, kob = tid >> 7;

    f32x4 acc[4][4];
#pragma unroll
    for (int i = 0; i < 4; ++i)
#pragma unroll
        for (int j = 0; j < 4; ++j) acc[i][j] = (f32x4){0.f, 0.f, 0.f, 0.f};

    const u16* wtile = Wimg + ((size_t)mtb * KT << 14);

    // invariant offsets (u16 units)
    const int afo = l4 * 2048 + (wm * 64 + l15) * 8;   // + mf*128, + plane*8192
    const int bfo = l4 * 1024 + (wn * 64 + l15) * 8;   // + nf*128, + plane*4096
    const int bwo = kob * 1024 + nb * 8;               // staging write

    float xr[8]; float2 ar[8];

#define STAGE_A(kt, buf)                                                          \
    {                                                                             \
        const u16* g_ = wtile + ((size_t)(kt) << 14);                             \
        u16* l_ = As_ + ((buf) << 14);                                            \
        _Pragma("unroll")                                                         \
        for (int i_ = 0; i_ < 4; ++i_)                                            \
            gload_lds16(g_ + wid * 2048 + i_ * 512 + lane * 8,                    \
                        l_ + wid * 2048 + i_ * 512);                              \
    }

#define READ_B(kt)                                                                \
    {                                                                             \
        const int kb_ = (kt) * 32 + kob * 8;                                      \
        const float* src_ = X + ((size_t)b * Kact + kb_) * NPTS + n0 + nb;        \
        _Pragma("unroll")                                                         \
        for (int j_ = 0; j_ < 8; ++j_) {                                          \
            const int k_ = kb_ + j_;                                              \
            xr[j_] = (k_ < Kact) ? src_[(size_t)j_ * NPTS] : 0.f;                 \
            if (BN_IN) ar[j_] = ash[(k_ < Kact) ? k_ : 0];                        \
        }                                                                         \
    }

#define WRITE_B()                                                                 \
    {                                                                             \
        u32 hh_[8], mm_[8];                                                       \
        _Pragma("unroll")                                                         \
        for (int j_ = 0; j_ < 8; ++j_) {                                          \
            float x_ = xr[j_];                                                    \
            if (BN_IN) x_ = fmaxf(fmaf(ar[j_].x, x_, ar[j_].y), 0.f);             \
            const u32 u_ = __float_as_uint(x_);                                   \
            const u32 uh_ = u_ + 0x8000u;                                         \
            const float r1_ = x_ - __uint_as_float(uh_ & 0xFFFF0000u);            \
            hh_[j_] = uh_;                                                        \
            mm_[j_] = __float_as_uint(r1_) + 0x8000u;                             \
        }                                                                         \
        uint4 wh_, wm_;                                                           \
        wh_.x = pk(hh_[0], hh_[1]); wh_.y = pk(hh_[2], hh_[3]);                   \
        wh_.z = pk(hh_[4], hh_[5]); wh_.w = pk(hh_[6], hh_[7]);                   \
        wm_.x = pk(mm_[0], mm_[1]); wm_.y = pk(mm_[2], mm_[3]);                   \
        wm_.z = pk(mm_[4], mm_[5]); wm_.w = pk(mm_[6], mm_[7]);                   \
        *(uint4*)(Bs_ + bwo)        = wh_;                                        \
        *(uint4*)(Bs_ + 4096 + bwo) = wm_;                                        \
    }

#define COMPUTE(buf)                                                              \
    {                                                                             \
        const u16* A_ = As_ + ((buf) << 14);                                      \
        short8 ah_[4], am_[4];                                                    \
        _Pragma("unroll")                                                         \
        for (int mf_ = 0; mf_ < 4; ++mf_) {                                       \
            ah_[mf_] = *(const short8*)(A_ + afo + mf_ * 128);                    \
            am_[mf_] = *(const short8*)(A_ + 8192 + afo + mf_ * 128);             \
        }                                                                         \
        _Pragma("unroll")                                                         \
        for (int nf_ = 0; nf_ < 4; ++nf_) {                                       \
            const short8 bh_ = *(const short8*)(Bs_ + bfo + nf_ * 128);           \
            const short8 bm_ = *(const short8*)(Bs_ + 4096 + bfo + nf_ * 128);    \
            _Pragma("unroll")                                                     \
            for (int mf_ = 0; mf_ < 4; ++mf_)                                     \
                acc[mf_][nf_] = __builtin_amdgcn_mfma_f32_16x16x32_bf16(          \
                    ah_[mf_], bh_, acc[mf_][nf_], 0, 0, 0);                       \
            _Pragma("unroll")                                                     \
            for (int mf_ = 0; mf_ < 4; ++mf_)                                     \
                acc[mf_][nf_] = __builtin_amdgcn_mfma_f32_16x16x32_bf16(          \
                    ah_[mf_], bm_, acc[mf_][nf_], 0, 0, 0);                       \
            _Pragma("unroll")                                                     \
            for (int mf_ = 0; mf_ < 4; ++mf_)                                     \
                acc[mf_][nf_] = __builtin_amdgcn_mfma_f32_16x16x32_bf16(          \
                    am_[mf_], bh_, acc[mf_][nf_], 0, 0, 0);                       \
        }                                                                         \
    }

    // prologue: A(0) and B(0) in flight
    STAGE_A(0, 0);
    READ_B(0);

    int cur = 0;
    for (int kt = 0; kt < KT; ++kt) {
        WRITE_B();                      // B(kt) regs -> LDS (BN+ReLU+split)
        __syncthreads();                // publish A[cur](kt) + B(kt)
        if (kt + 1 < KT) {
            STAGE_A(kt + 1, cur ^ 1);   // async; flies under COMPUTE
            READ_B(kt + 1);             // reg prefetch; flies under COMPUTE
        }
        COMPUTE(cur);
        if (kt + 1 < KT) __syncthreads();   // Bs reusable; drains prefetches (post-compute)
        cur ^= 1;
    }

    // ---- epilogue: bias, stats partials, optional store / max-min partials ----
#pragma unroll
    for (int mf = 0; mf < 4; ++mf) {
#pragma unroll
        for (int r = 0; r < 4; ++r) {
            const int m = m0 + wm * 64 + mf * 16 + l4 * 4 + r;
            const float bvv = bias[m];
            float vs[4];
            float rs = 0.f, rq = 0.f;
#pragma unroll
            for (int nf = 0; nf < 4; ++nf) {
                const float v = acc[mf][nf][r] + bvv;
                vs[nf] = v; rs += v; rq = fmaf(v, v, rq);
            }
            float mx = 0.f, mn = 0.f;
            if (MAXMIN) {
                mx = fmaxf(fmaxf(vs[0], vs[1]), fmaxf(vs[2], vs[3]));
                mn = fminf(fminf(vs[0], vs[1]), fminf(vs[2], vs[3]));
            }
            if (STORE) {
#pragma unroll
                for (int nf = 0; nf < 4; ++nf)
                    Y[((size_t)b * M_ + m) * NPTS + n0 + wn * 64 + nf * 16 + l15] = vs[nf];
            }
#pragma unroll
            for (int s = 1; s < 16; s <<= 1) {
                rs += __shfl_xor(rs, s);
                rq += __shfl_xor(rq, s);
                if (MAXMIN) {
                    mx = fmaxf(mx, __shfl_xor(mx, s));
                    mn = fminf(mn, __shfl_xor(mn, s));
                }
            }
            if (l15 == 0) {
                const int slot = (b * 32 + nt) * 2 + wn;
                psum[(size_t)slot * M_ + m] = rs;
                psq[(size_t)slot * M_ + m]  = rq;
                if (MAXMIN) {
                    pmax[((size_t)b * M_ + m) * 64 + nt * 2 + wn] = mx;
                    pmin[((size_t)b * M_ + m) * 64 + nt * 2 + wn] = mn;
                }
            }
        }
    }
#undef STAGE_A
#undef READ_B
#undef WRITE_B
#undef COMPUTE
}

// ---- per-channel stats (1024 slots) -> BN scale/shift (packed float2) ----
__global__ __launch_bounds__(256) void stats_k(const float* __restrict__ psum, const float* __restrict__ psq,
                                               int M_,
                                               const float* __restrict__ g, const float* __restrict__ be,
                                               float2* __restrict__ ash)
{
    __shared__ double ds[4][64];
    __shared__ double dq[4][64];
    const int mloc = threadIdx.x & 63, q = threadIdx.x >> 6;
    const int m = blockIdx.x * 64 + mloc;
    double s = 0.0, sq = 0.0;
    for (int sl = q * 256; sl < (q + 1) * 256; ++sl) {
        s  += (double)psum[(size_t)sl * M_ + m];
        sq += (double)psq[(size_t)sl * M_ + m];
    }
    ds[q][mloc] = s; dq[q][mloc] = sq;
    __syncthreads();
    if (threadIdx.x < 64) {
        const double S = ds[0][mloc] + ds[1][mloc] + ds[2][mloc] + ds[3][mloc];
        const double Q = dq[0][mloc] + dq[1][mloc] + dq[2][mloc] + dq[3][mloc];
        const double cnt = (double)NB * (double)NPTS;
        double mean = S / cnt;
        double var  = Q / cnt - mean * mean;
        if (var < 0.0) var = 0.0;
        const double a = (double)g[m] / sqrt(var + 1e-5);
        ash[m] = make_float2((float)a, (float)((double)be[m] - a * mean));
    }
}

// ---- final: fused L3-stats, pool-select, BN-apply+ReLU, BN1d over batch ----
__global__ __launch_bounds__(256) void final_k(const float* __restrict__ psum, const float* __restrict__ psq,
                                               const float* __restrict__ g3, const float* __restrict__ be3,
                                               const float* __restrict__ pmax, const float* __restrict__ pmin,
                                               const float* __restrict__ g4, const float* __restrict__ be4,
                                               float* __restrict__ out)
{
    const int c = blockIdx.x * 256 + threadIdx.x;
    if (c >= 1024) return;
    double S = 0.0, Q = 0.0;
    for (int sl = 0; sl < 1024; ++sl) {
        S += (double)psum[(size_t)sl * 1024 + c];
        Q += (double)psq[(size_t)sl * 1024 + c];
    }
    const double cnt = (double)NB * (double)NPTS;
    double mean3 = S / cnt;
    double var3  = Q / cnt - mean3 * mean3;
    if (var3 < 0.0) var3 = 0.0;
    const double a3 = (double)g3[c] / sqrt(var3 + 1e-5);
    const float a = (float)a3;
    const float sh = (float)((double)be3[c] - a3 * mean3);

    float h[NB];
    float s = 0.f;
    for (int b = 0; b < NB; ++b) {
        float mxv = -FLT_BIG, mnv = FLT_BIG;
        const float* pxr = pmax + ((size_t)b * 1024 + c) * 64;
        const float* pnr = pmin + ((size_t)b * 1024 + c) * 64;
        for (int q = 0; q < 64; ++q) {
            mxv = fmaxf(mxv, pxr[q]);
            mnv = fminf(mnv, pnr[q]);
        }
        const float v = (a >= 0.f) ? fmaf(a, mxv, sh) : fmaf(a, mnv, sh);
        h[b] = fmaxf(v, 0.f);
        s += h[b];
    }
    const float mean = s * (1.f / NB);
    float var = 0.f;
    for (int b = 0; b < NB; ++b) { const float d = h[b] - mean; var = fmaf(d, d, var); }
    var *= (1.f / NB);
    const double ai = (double)g4[c] / sqrt((double)var + 1e-5);
    for (int b = 0; b < NB; ++b)
        out[b * 1024 + c] = (float)(ai * ((double)h[b] - (double)mean) + (double)be4[c]);
}

extern "C" void kernel_launch(void* const* d_in, const int* in_sizes, int n_in,
                              void* d_out, int out_size, void* d_ws, size_t ws_size,
                              hipStream_t stream) {
    const float* xyz = (const float*)d_in[0];
    const float* W1  = (const float*)d_in[1];
    const float* b1  = (const float*)d_in[2];
    const float* g1  = (const float*)d_in[3];
    const float* be1 = (const float*)d_in[4];
    const float* W2  = (const float*)d_in[5];
    const float* b2  = (const float*)d_in[6];
    const float* g2  = (const float*)d_in[7];
    const float* be2 = (const float*)d_in[8];
    const float* W3  = (const float*)d_in[9];
    const float* b3  = (const float*)d_in[10];
    const float* g3  = (const float*)d_in[11];
    const float* be3 = (const float*)d_in[12];
    const float* g4  = (const float*)d_in[13];
    const float* be4 = (const float*)d_in[14];

    float* ws = (float*)d_ws;
    float* y1  = ws + OFF_Y1;
    float* y2  = ws + OFF_Y2;
    u16*   w1i = (u16*)(ws + OFF_W1I);
    u16*   w2i = (u16*)(ws + OFF_W2I);
    u16*   w3i = (u16*)(ws + OFF_W3I);
    float* ps  = ws + OFF_PS;
    float* pq  = ws + OFF_PQ;
    float* pmx = ws + OFF_PMX;
    float* pmn = ws + OFF_PMN;
    float2* ash = (float2*)(ws + OFF_ASH);
    float* out = (float*)d_out;

    // W images: L1 21 tiles, L2 16, L3 64
    prep_w<<<101, 256, 0, stream>>>(W1, W2, W3, w1i, w2i, w3i);

    // L1: y1 = W1 @ xyz + b1 (store + stats). grid (nt=32, mtb=1, b=16)
    gemm3p<false, true, false><<<dim3(32, 1, 16), 512, 0, stream>>>(
        w1i, 21, 643, 256, b1, xyz, nullptr,
        y1, ps, pq, nullptr, nullptr);
    stats_k<<<4, 256, 0, stream>>>(ps, pq, 256, g1, be1, ash);

    // L2: y2 = W2 @ relu(bn(y1)) + b2 (store + stats). grid (32, 2, 16)
    gemm3p<true, true, false><<<dim3(32, 2, 16), 512, 0, stream>>>(
        w2i, 8, 256, 512, b2, y1, ash,
        y2, ps, pq, nullptr, nullptr);
    stats_k<<<8, 256, 0, stream>>>(ps, pq, 512, g2, be2, ash);

    // L3: stats + per-(b,m) max/min partials (no store). grid (32, 4, 16)
    gemm3p<true, false, true><<<dim3(32, 4, 16), 512, 0, stream>>>(
        w3i, 16, 512, 1024, b3, y2, ash,
        nullptr, ps, pq, pmx, pmn);

    // fused L3-stats + pool-select + final BN1d
    final_k<<<4, 256, 0, stream>>>(ps, pq, g3, be3, pmx, pmn, g4, be4, out);
}